// Round 6
// baseline (5595.256 us; speedup 1.0000x reference)
//
#include <hip/hip_runtime.h>

// ---------------- problem constants ----------------
#define BATCH 64
#define SLEN  512
#define EDIM  512
#define HDIM  1024
#define NBLK  256
#define HALF  128                // blocks per layer group
#define K0    (EDIM + HDIM)      // 1536  layer0 K
#define K1    (2 * HDIM)         // 2048  layer1 K
#define ROWB  4096               // LDS bytes per weight row
#define ZR    32                 // z-rows per block = 4 gates x 8 h-cols
#define ZST   68                 // zbuf batch-row stride (2 nt-partials of 34)
#define HB    (BATCH * HDIM)     // elems per h slot (65536; 128 KiB bf16)
#define RING  8                  // fallback ring depth

#define XE_BYTES ((size_t)SLEN * BATCH * EDIM * 2)      // 32 MiB
#define HBUF_BIG ((size_t)SLEN * HB * 2)                // 64 MiB per layer
#define HBUF_SML ((size_t)RING * HB * 2)                // 1 MiB per layer

typedef __bf16 bf16x8 __attribute__((ext_vector_type(8)));
typedef float  f32x4  __attribute__((ext_vector_type(4)));
typedef unsigned u32x4 __attribute__((ext_vector_type(4)));

__device__ __forceinline__ float sigm(float x) { return 1.0f / (1.0f + __expf(-x)); }
__device__ __forceinline__ float tanhfast(float x) {
  float e = __expf(-2.0f * __builtin_fabsf(x));
  float r = (1.0f - e) / (1.0f + e);
  return x < 0.0f ? -r : r;
}

// 16B write-through store (visible at L3 once vmcnt drains; never dirty in L2)
__device__ __forceinline__ void st16_wt(__bf16* p, unsigned d0, unsigned d1,
                                        unsigned d2, unsigned d3) {
  u32x4 v = {d0, d1, d2, d3};
  asm volatile("global_store_dwordx4 %0, %1, off sc0 sc1" :: "v"(p), "v"(v) : "memory");
}

// L2-bypassing 16B load (fallback ring path only)
__device__ __forceinline__ bf16x8 ald16(const __bf16* p) {
  union { unsigned long long q[2]; bf16x8 v; } u;
  u.q[0] = __hip_atomic_load((const unsigned long long*)p,       __ATOMIC_RELAXED, __HIP_MEMORY_SCOPE_AGENT);
  u.q[1] = __hip_atomic_load((const unsigned long long*)(p + 4), __ATOMIC_RELAXED, __HIP_MEMORY_SCOPE_AGENT);
  return u.v;
}

template<int BIG>
__device__ __forceinline__ bf16x8 hload(const __bf16* p) {
  if constexpr (BIG) return *(const bf16x8*)p;   // normal load: L2-cached, multicast
  else return ald16(p);                          // ring mode: must bypass (slot reuse)
}

// Block-level wait. HOT busy-spin (no s_sleep): keeping issue activity up holds
// SCLK up (DPM downclock hypothesis). Wave 0 polls the 128 global flags,
// releases waves 1-7 via an LDS gate.
__device__ __forceinline__ void block_wait(const int* f, int target, int* gate) {
  if (target <= 0) return;
  if ((threadIdx.x >> 6) == 0) {
    if (__hip_atomic_load(gate, __ATOMIC_RELAXED, __HIP_MEMORY_SCOPE_WORKGROUP) < target) {
      const int l = threadIdx.x & 63;
      int tries = 0;
      while (true) {
        int v0 = __hip_atomic_load(f + l,      __ATOMIC_RELAXED, __HIP_MEMORY_SCOPE_AGENT);
        int v1 = __hip_atomic_load(f + l + 64, __ATOMIC_RELAXED, __HIP_MEMORY_SCOPE_AGENT);
        if (__all((v0 >= target) && (v1 >= target))) break;
        if (++tries > (1 << 22)) break;   // anti-hang safety net (~0.5s worst case)
      }
      if (l == 0)
        __hip_atomic_fetch_max(gate, target, __ATOMIC_RELEASE, __HIP_MEMORY_SCOPE_WORKGROUP);
    }
  } else {
    int tries = 0;
    while (__hip_atomic_load(gate, __ATOMIC_ACQUIRE, __HIP_MEMORY_SCOPE_WORKGROUP) < target) {
      if (++tries > (1 << 25)) break;
    }
  }
}

// ---- xe = bf16(emb[x]) laid out [t][b][e] ----
__global__ void xe_gather(const int* __restrict__ x, const float* __restrict__ emb,
                          __bf16* __restrict__ xe) {
  int g = blockIdx.x * blockDim.x + threadIdx.x;
  if (g >= SLEN * BATCH * (EDIM / 8)) return;
  int e8 = g & 63, bt = g >> 6;
  int b = bt & 63, t = bt >> 6;
  int tok = x[b * SLEN + t];
  const float* er = emb + (size_t)tok * EDIM + e8 * 8;
  f32x4 v0 = *(const f32x4*)er, v1 = *(const f32x4*)(er + 4);
  bf16x8 o = { (__bf16)v0[0], (__bf16)v0[1], (__bf16)v0[2], (__bf16)v0[3],
               (__bf16)v1[0], (__bf16)v1[1], (__bf16)v1[2], (__bf16)v1[3] };
  *(bf16x8*)(xe + ((size_t)t * BATCH + b) * EDIM + e8 * 8) = o;
}

// Persistent skewed 2-layer LSTM. BIG=1: write-once per-step h slots, consumers
// use normal (L2-multicast) loads. BIG=0: 8-slot ring + bypass loads.
// L0 is software-pipelined: step s+1's xe-part overlaps step s's store drain.
template<int BIG>
__global__ __launch_bounds__(512, 2) void lstm_persistent(
    const int* __restrict__ x, const float* __restrict__ emb,
    const float* __restrict__ Wx0, const float* __restrict__ bx0,
    const float* __restrict__ Wh0, const float* __restrict__ bh0,
    const float* __restrict__ Wx1, const float* __restrict__ bx1,
    const float* __restrict__ Wh1, const float* __restrict__ bh1,
    const __bf16* __restrict__ xe, int use_xe,
    __bf16* h0buf, __bf16* h1buf, int* f0, int* f1)
{
  __shared__ __align__(16) unsigned char Ws[ZR * ROWB];   // 128 KiB
  __shared__ float zbuf[BATCH * ZST];                     // 17 KiB
  __shared__ float bias[ZR];
  __shared__ int gateF0, gateF1;

  const int tid   = threadIdx.x;
  const int wg    = blockIdx.x;
  const int layer = wg >> 7;
  const int sub   = wg & (HALF - 1);

  if (tid == 0) { gateF0 = 0; gateF1 = 0; }

  // ---- stage this block's 32 weight rows (bf16, XOR-swizzled) ----
  if (layer == 0) {
    for (int idx = tid; idx < ZR * K0; idx += 512) {
      int n = idx / K0, k = idx - n * K0;
      int grow = (n >> 3) * HDIM + sub * 8 + (n & 7);
      float v = (k < EDIM) ? Wx0[grow * EDIM + k] : Wh0[grow * HDIM + (k - EDIM)];
      *(__bf16*)(&Ws[n * ROWB + (((unsigned)(k << 1)) ^ (unsigned)((n & 7) << 4))]) = (__bf16)v;
    }
    if (tid < ZR) {
      int grow = (tid >> 3) * HDIM + sub * 8 + (tid & 7);
      bias[tid] = bx0[grow] + bh0[grow];
    }
  } else {
    for (int idx = tid; idx < ZR * K1; idx += 512) {
      int n = idx >> 11, k = idx & (K1 - 1);
      int grow = (n >> 3) * HDIM + sub * 8 + (n & 7);
      float v = (k < HDIM) ? Wx1[grow * HDIM + k] : Wh1[grow * HDIM + (k - HDIM)];
      *(__bf16*)(&Ws[n * ROWB + (((unsigned)(k << 1)) ^ (unsigned)((n & 7) << 4))]) = (__bf16)v;
    }
    if (tid < ZR) {
      int grow = (tid >> 3) * HDIM + sub * 8 + (tid & 7);
      bias[tid] = bx1[grow] + bh1[grow];
    }
  }
  __syncthreads();

  const int lane = tid & 63, wave = tid >> 6;
  const int mrow = lane & 15;
  const int q    = lane >> 4;
  const int mt   = wave >> 1, nt = wave & 1;   // 4 batch-tiles x 2 K-split halves
  const int brow = mt * 16 + mrow;
  const unsigned brb0 = (unsigned)(mrow * ROWB);          // z-cols 0..15
  const unsigned brb1 = (unsigned)((16 + mrow) * ROWB);   // z-cols 16..31
  const unsigned bsw  = (unsigned)((mrow & 7) << 4);
  const int bg = tid >> 3, jl = tid & 7;
  const int zrow = mt * 16 + q * 4;

  float cst = 0.0f;

#define SLOT(s)  ((size_t)(BIG ? (s) : ((s) & (RING - 1))) * HB)
#define LDSB(brb, koff) (*(const bf16x8*)(&Ws[(brb) + (((unsigned)((((koff) << 1)) + (q << 4))) ^ bsw)]))
#define MFMA(a, b, c) __builtin_amdgcn_mfma_f32_16x16x32_bf16(a, b, c, 0, 0, 0)

// xe-part of step (sidx), accumulated into A0/A1
#define XE_PART(sidx, A0, A1)                                                     \
  do {                                                                            \
    if (use_xe) {                                                                 \
      const __bf16* aX = xe + ((size_t)(sidx) * BATCH + brow) * EDIM;             \
      _Pragma("unroll 4")                                                         \
      for (int k0 = nt * 32; k0 < EDIM; k0 += 64) {                               \
        bf16x8 a = *(const bf16x8*)(aX + k0 + q * 8);                             \
        A0 = MFMA(a, LDSB(brb0, k0), A0);                                         \
        A1 = MFMA(a, LDSB(brb1, k0), A1);                                         \
      }                                                                           \
    } else {                                                                      \
      const int tok = x[brow * SLEN + (sidx)];                                    \
      const float* erow = emb + (size_t)tok * EDIM;                               \
      _Pragma("unroll 4")                                                         \
      for (int k0 = nt * 32; k0 < EDIM; k0 += 64) {                               \
        f32x4 e0 = *(const f32x4*)(erow + k0 + q * 8);                            \
        f32x4 e1 = *(const f32x4*)(erow + k0 + q * 8 + 4);                        \
        bf16x8 a = { (__bf16)e0[0], (__bf16)e0[1], (__bf16)e0[2], (__bf16)e0[3],  \
                     (__bf16)e1[0], (__bf16)e1[1], (__bf16)e1[2], (__bf16)e1[3] };\
        A0 = MFMA(a, LDSB(brb0, k0), A0);                                         \
        A1 = MFMA(a, LDSB(brb1, k0), A1);                                         \
      }                                                                           \
    }                                                                             \
  } while (0)

// gates from zbuf (after syncthreads) -> h value -> packed 16B wt store (jl==0)
#define GATES_AND_STORE(hdst, slotExpr)                                           \
  do {                                                                            \
    float zf = zbuf[bg*ZST +      jl] + zbuf[bg*ZST + 34 +      jl] + bias[     jl]; \
    float zi = zbuf[bg*ZST +  8 + jl] + zbuf[bg*ZST + 34 +  8 + jl] + bias[ 8 + jl]; \
    float zg = zbuf[bg*ZST + 16 + jl] + zbuf[bg*ZST + 34 + 16 + jl] + bias[16 + jl]; \
    float zo = zbuf[bg*ZST + 24 + jl] + zbuf[bg*ZST + 34 + 24 + jl] + bias[24 + jl]; \
    float fg = sigm(zf), ig = sigm(zi), gg = tanhfast(zg), og = sigm(zo);         \
    cst = fg * cst + ig * gg;                                                     \
    __bf16 hv = (__bf16)(og * tanhfast(cst));                                     \
    unsigned short us = __builtin_bit_cast(unsigned short, hv);                   \
    unsigned pw = ((unsigned)us) | (((unsigned)(unsigned short)__shfl_xor((int)us, 1, 64)) << 16); \
    unsigned d1 = (unsigned)__shfl_xor((int)pw, 2, 64);                           \
    unsigned d2 = (unsigned)__shfl_xor((int)pw, 4, 64);                           \
    unsigned d3 = (unsigned)__shfl_xor((int)pw, 6, 64);                           \
    if (jl == 0)                                                                  \
      st16_wt(hdst + (slotExpr) + bg * HDIM + sub * 8, pw, d1, d2, d3);           \
  } while (0)

  if (layer == 0) {
    // prologue: xe-part of step 0
    f32x4 xac0 = {0.f,0.f,0.f,0.f}, xac1 = {0.f,0.f,0.f,0.f};
    XE_PART(0, xac0, xac1);
    for (int s = 0; s < SLEN; ++s) {
      f32x4 acc0 = xac0, acc1 = xac1;
      // --- h0(s-1) part (the recurrence-critical GEMM) ---
      if (s > 0) {
        block_wait(f0, s, &gateF0);
        const __bf16* hp = h0buf + SLOT(s - 1) + brow * HDIM + nt * 32 + q * 8;
        const int kb = EDIM + nt * 32;
        #pragma unroll
        for (int i = 0; i < 16; ++i) {
          bf16x8 a = hload<BIG>(hp + i * 64);
          acc0 = MFMA(a, LDSB(brb0, kb + i*64), acc0);
          acc1 = MFMA(a, LDSB(brb1, kb + i*64), acc1);
        }
      }
      #pragma unroll
      for (int r = 0; r < 4; ++r) {
        zbuf[(zrow + r) * ZST + nt * 34 + mrow]      = acc0[r];
        zbuf[(zrow + r) * ZST + nt * 34 + 16 + mrow] = acc1[r];
      }
      __syncthreads();
      if constexpr (!BIG) {   // ring anti-dep: slot reused after RING steps
        if (s >= RING) { block_wait(f1, s - RING + 2, &gateF1); block_wait(f0, s - RING + 2, &gateF0); }
      }
      GATES_AND_STORE(h0buf, SLOT(s));
      // --- next step's xe-part overlaps the store drain ---
      xac0 = (f32x4){0.f,0.f,0.f,0.f}; xac1 = (f32x4){0.f,0.f,0.f,0.f};
      if (s + 1 < SLEN) XE_PART(s + 1, xac0, xac1);
      asm volatile("s_waitcnt vmcnt(0)" ::: "memory");   // h store (and xe loads) drained
      __syncthreads();                                   // all waves drained
      if (tid == 0)
        __hip_atomic_store(&f0[sub], s + 1, __ATOMIC_RELAXED, __HIP_MEMORY_SCOPE_AGENT);
    }
  } else {
    for (int j = 0; j < SLEN; ++j) {
      f32x4 acc0 = {0.f,0.f,0.f,0.f}, acc1 = {0.f,0.f,0.f,0.f};
      // --- h1(j-1) part (own-group flags usually already set) ---
      if (j > 0) {
        block_wait(f1, j, &gateF1);
        const __bf16* hp = h1buf + SLOT(j - 1) + brow * HDIM + nt * 32 + q * 8;
        const int kb = HDIM + nt * 32;
        #pragma unroll
        for (int i = 0; i < 16; ++i) {
          bf16x8 a = hload<BIG>(hp + i * 64);
          acc0 = MFMA(a, LDSB(brb0, kb + i*64), acc0);
          acc1 = MFMA(a, LDSB(brb1, kb + i*64), acc1);
        }
      }
      // --- h0(j) part ---
      block_wait(f0, j + 1, &gateF0);
      {
        const __bf16* hp = h0buf + SLOT(j) + brow * HDIM + nt * 32 + q * 8;
        const int kb = nt * 32;
        #pragma unroll
        for (int i = 0; i < 16; ++i) {
          bf16x8 a = hload<BIG>(hp + i * 64);
          acc0 = MFMA(a, LDSB(brb0, kb + i*64), acc0);
          acc1 = MFMA(a, LDSB(brb1, kb + i*64), acc1);
        }
      }
      #pragma unroll
      for (int r = 0; r < 4; ++r) {
        zbuf[(zrow + r) * ZST + nt * 34 + mrow]      = acc0[r];
        zbuf[(zrow + r) * ZST + nt * 34 + 16 + mrow] = acc1[r];
      }
      __syncthreads();
      if constexpr (!BIG) {
        if (j >= RING) block_wait(f1, j - RING + 2, &gateF1);
      }
      GATES_AND_STORE(h1buf, SLOT(j));
      asm volatile("s_waitcnt vmcnt(0)" ::: "memory");
      __syncthreads();
      if (tid == 0)
        __hip_atomic_store(&f1[sub], j + 1, __ATOMIC_RELAXED, __HIP_MEMORY_SCOPE_AGENT);
    }
  }
}

// ---- final FC: out[b] = sigmoid(h1(511) . fcw + fcb) ----
__global__ void fc_kernel(const __bf16* __restrict__ h1slot,
                          const float* __restrict__ fcw, const float* __restrict__ fcb,
                          float* __restrict__ out) {
  __shared__ float part[512];
  const int tid = threadIdx.x, b = tid >> 3, q2 = tid & 7;
  const __bf16* hr = h1slot + b * HDIM + q2 * 128;
  const float*  wr = fcw + q2 * 128;
  float acc = 0.0f;
  for (int k = 0; k < 128; k += 8) {
    bf16x8 hvv = *(const bf16x8*)(hr + k);   // fresh dispatch: caches invalidated
    #pragma unroll
    for (int i = 0; i < 8; ++i) acc += (float)hvv[i] * wr[k + i];
  }
  part[tid] = acc;
  __syncthreads();
  if (tid < BATCH) {
    float s = fcb[0];
    #pragma unroll
    for (int i = 0; i < 8; ++i) s += part[tid * 8 + i];
    out[tid] = 1.0f / (1.0f + __expf(-s));
  }
}

extern "C" void kernel_launch(void* const* d_in, const int* in_sizes, int n_in,
                              void* d_out, int out_size, void* d_ws, size_t ws_size,
                              hipStream_t stream) {
  (void)in_sizes; (void)n_in; (void)out_size;
  const int*   x   = (const int*)  d_in[0];
  const float* emb = (const float*)d_in[1];
  const float* Wx0 = (const float*)d_in[2];
  const float* bx0 = (const float*)d_in[3];
  const float* Wh0 = (const float*)d_in[4];
  const float* bh0 = (const float*)d_in[5];
  const float* Wx1 = (const float*)d_in[6];
  const float* bx1 = (const float*)d_in[7];
  const float* Wh1 = (const float*)d_in[8];
  const float* bh1 = (const float*)d_in[9];
  const float* fcw = (const float*)d_in[10];
  const float* fcb = (const float*)d_in[11];
  float* out = (float*)d_out;

  char* ws = (char*)d_ws;
  int* f0 = (int*)(ws);
  int* f1 = (int*)(ws + 512);

  const size_t need_big = 4096 + 2 * HBUF_BIG + XE_BYTES;           // ~160.1 MiB
  const size_t need_sml = 4096 + 2 * HBUF_SML + XE_BYTES;           // ~34.1 MiB
  const int big    = (ws_size >= need_big) ? 1 : 0;
  const size_t hbytes = big ? HBUF_BIG : HBUF_SML;
  __bf16* h0buf = (__bf16*)(ws + 4096);
  __bf16* h1buf = (__bf16*)(ws + 4096 + hbytes);
  __bf16* xe    = (__bf16*)(ws + 4096 + 2 * hbytes);
  const int use_xe = (big || ws_size >= need_sml) ? 1 : 0;

  hipMemsetAsync(d_ws, 0, 4096, stream);   // flags only
  if (use_xe) {
    const int groups = SLEN * BATCH * (EDIM / 8);
    xe_gather<<<(groups + 255) / 256, 256, 0, stream>>>(x, emb, xe);
  }
  if (big) {
    lstm_persistent<1><<<NBLK, 512, 0, stream>>>(x, emb, Wx0, bx0, Wh0, bh0,
                                                 Wx1, bx1, Wh1, bh1,
                                                 xe, use_xe, h0buf, h1buf, f0, f1);
    fc_kernel<<<1, 512, 0, stream>>>(h1buf + (size_t)(SLEN - 1) * HB, fcw, fcb, out);
  } else {
    lstm_persistent<0><<<NBLK, 512, 0, stream>>>(x, emb, Wx0, bx0, Wh0, bh0,
                                                 Wx1, bx1, Wh1, bh1,
                                                 xe, use_xe, h0buf, h1buf, f0, f1);
    fc_kernel<<<1, 512, 0, stream>>>(h1buf + (size_t)((SLEN - 1) & (RING - 1)) * HB, fcw, fcb, out);
  }
}